// Round 7
// baseline (669.926 us; speedup 1.0000x reference)
//
#include <hip/hip_runtime.h>
#include <hip/hip_bf16.h>
#include <stdint.h>

// ---------------------------------------------------------------------------
// RegressionNet: cost-volume + 3x conv-BN-relu + 2x FC, bf16 MFMA pipeline.
// R6: convs ported to the verified m201 8-phase schedule (T2+T3+T4+T5):
//     256x256x64 tiles, 2-way K-split, dbuf 128KiB LDS, per phase
//     {ds_read | stage half-tile -> barrier -> lgkmcnt(0) -> setprio ->
//      16 MFMA -> barrier}, staging skewed P1-P3/P5-P7, vmcnt(0) only at
//     P4/P8 (last loads >=2 phases old). Everything else identical to R5.
// ---------------------------------------------------------------------------

typedef unsigned short ushort_t;
typedef __attribute__((ext_vector_type(8))) short     bf16x8;
typedef __attribute__((ext_vector_type(8))) unsigned short u16x8;
typedef __attribute__((ext_vector_type(4))) unsigned short u16x4;
typedef __attribute__((ext_vector_type(4))) float     f32x4;

#define NB   64
#define NC   256
#define NP   256
#define KCV  256
#define KP1  1152
#define NOUT 512
#define NROWS 16384
#define KFC  131072
#define NF   1024
#define KSPL 32      // fc1 k-splits

__device__ __forceinline__ unsigned short f2bf(float x) {
  union { float f; unsigned u; } c; c.f = x;
  unsigned r = c.u + 0x7FFFu + ((c.u >> 16) & 1u);
  return (unsigned short)(r >> 16);
}
__device__ __forceinline__ float b2f(unsigned short u) {
  union { unsigned u; float f; } c; c.u = ((unsigned)u) << 16; return c.f;
}

__device__ __forceinline__ void gl_lds16(const void* g, void* l) {
  __builtin_amdgcn_global_load_lds(
      (const __attribute__((address_space(1))) unsigned int*)g,
      (__attribute__((address_space(3))) unsigned int*)l, 16, 0, 0);
}

__device__ __forceinline__ f32x4 mfma16(bf16x8 a, bf16x8 b, f32x4 c) {
  return __builtin_amdgcn_mfma_f32_16x16x32_bf16(a, b, c, 0, 0, 0);
}

// ---------------------------------------------------------------------------
// l2-normalize over channels; write pos-major bf16 [b][pos][c].
// ---------------------------------------------------------------------------
__global__ __launch_bounds__(256) void l2norm_t(
    const float* __restrict__ f1, const float* __restrict__ f2,
    ushort_t* __restrict__ AT, ushort_t* __restrict__ N2T)
{
  const float* src = blockIdx.y ? f2 : f1;
  ushort_t*    dst = blockIdx.y ? N2T : AT;
  const int b = blockIdx.x, t = threadIdx.x;
  const float* sb = src + (size_t)b * NC * NP;
  float sq = 0.f;
  for (int c = 0; c < NC; ++c) { float v = sb[c * NP + t]; sq += v * v; }
  float sc = 1.f / fmaxf(sqrtf(sq), 1e-12f);
  ushort_t* db = dst + ((size_t)b * NP + t) * NC;
  for (int c0 = 0; c0 < NC; c0 += 8) {
    u16x8 pk;
#pragma unroll
    for (int q = 0; q < 8; ++q) pk[q] = f2bf(sb[(c0 + q) * NP + t] * sc);
    *(u16x8*)(db + c0) = pk;
  }
}

// ---------------------------------------------------------------------------
// Pack conv weights (OUT, Cin, 3, 3) fp32 -> [tap][out][cin(pad Kp)] bf16.
// ---------------------------------------------------------------------------
__global__ __launch_bounds__(256) void pack_w(
    const float* __restrict__ W, ushort_t* __restrict__ Wp,
    int Cin, int Kp, int total)
{
  int p = blockIdx.x * 256 + threadIdx.x;
  if (p >= total) return;
  int tap = p / (NOUT * Kp);
  int rem = p - tap * (NOUT * Kp);
  int o   = rem / Kp;
  int cin = rem - o * Kp;
  float v = (cin < Cin) ? W[((size_t)o * Cin + cin) * 9 + tap] : 0.f;
  Wp[p] = f2bf(v);
}

// ---------------------------------------------------------------------------
// Cost volume: per-b GEMM (pos x uv over channels), band-gather epilogue.
// ---------------------------------------------------------------------------
__global__ __launch_bounds__(256) void cv_gemm(
    const ushort_t* __restrict__ AT,
    const ushort_t* __restrict__ N2T,
    ushort_t* __restrict__ costT,
    const ushort_t* __restrict__ zerot)
{
  __shared__ ushort_t As[128 * 64];
  __shared__ ushort_t Bs[128 * 64];
  const int tid = threadIdx.x, lane = tid & 63, wave = tid >> 6;
  const int wr = wave >> 1, wc = wave & 1;
  const int la = lane & 15, lb = lane >> 4;
  const int b  = blockIdx.z;
  const int m0 = blockIdx.y * 128;
  const int n0 = blockIdx.x * 128;

  {
    const int iMin = blockIdx.y * 8, iMax = iMin + 7;
    const int uMin = n0 / 48, uMax = (n0 + 127) / 48;
    if (uMax < iMin || uMin > iMax + 32) return;
  }

  f32x4 acc[4][4];
#pragma unroll
  for (int i = 0; i < 4; ++i)
#pragma unroll
    for (int j = 0; j < 4; ++j) acc[i][j] = (f32x4){0.f, 0.f, 0.f, 0.f};

  const ushort_t* srcA[4];
  const ushort_t* srcB[4];
#pragma unroll
  for (int s = 0; s < 4; ++s) {
    int idx = tid + (s << 8);
    int row = idx >> 3, c16 = idx & 7;
    srcA[s] = AT + ((size_t)b * NP + m0 + row) * NC + c16 * 8;
    int uv = n0 + row;
    int u = uv / 48, v = uv - u * 48;
    int oi = u - 16, oj = v - 16;
    bool val = ((unsigned)oi < 16u) & ((unsigned)oj < 16u);
    srcB[s] = val ? (N2T + ((size_t)b * NP + oi * 16 + oj) * NC + c16 * 8)
                  : (const ushort_t*)0;
  }

  for (int kc = 0; kc < KCV; kc += 64) {
#pragma unroll
    for (int s = 0; s < 4; ++s) {
      int idx = tid + (s << 8);
      gl_lds16(srcA[s] + kc, &As[idx * 8]);
      const ushort_t* g = srcB[s] ? srcB[s] + kc : zerot;
      gl_lds16(g, &Bs[idx * 8]);
    }
    __syncthreads();
#pragma unroll
    for (int kk = 0; kk < 2; ++kk) {
      bf16x8 af[4], bfv[4];
#pragma unroll
      for (int mi = 0; mi < 4; ++mi)
        af[mi] = *(const bf16x8*)&As[(wr * 64 + mi * 16 + la) * 64 + kk * 32 + lb * 8];
#pragma unroll
      for (int ni = 0; ni < 4; ++ni)
        bfv[ni] = *(const bf16x8*)&Bs[(wc * 64 + ni * 16 + la) * 64 + kk * 32 + lb * 8];
#pragma unroll
      for (int mi = 0; mi < 4; ++mi)
#pragma unroll
        for (int ni = 0; ni < 4; ++ni)
          acc[mi][ni] = mfma16(af[mi], bfv[ni], acc[mi][ni]);
    }
    __syncthreads();
  }

  const float sc = 1.f / 256.f;
#pragma unroll
  for (int ni = 0; ni < 4; ++ni) {
    int uv = n0 + wc * 64 + ni * 16 + la;
    int u = uv / 48, v = uv - u * 48;
#pragma unroll
    for (int mi = 0; mi < 4; ++mi) {
      int ij = m0 + wr * 64 + mi * 16 + lb * 4;
#pragma unroll
      for (int r = 0; r < 4; ++r) {
        int ijr = ij + r;
        int i = ijr >> 4, j = ijr & 15;
        int dy = u - i, dx = v - j;
        if ((unsigned)dy < 33u && (unsigned)dx < 33u) {
          float vv = acc[mi][ni][r] * sc;
          vv = vv > 0.f ? vv : 0.01f * vv;
          costT[((size_t)b * NP + ijr) * KP1 + dy * 33 + dx] = f2bf(vv);
        }
      }
    }
  }
}

// ---------------------------------------------------------------------------
// Conv 3x3 tap-decomposed GEMM on the m201 8-phase schedule.
// BM=256(=image), BN=256, BK=64; 2-way K-split (grid 256); block 512 = 8 waves
// (2M x 4N), per-wave 128x64 out. LDS = 2 x (A 32KB + B 32KB) = 128 KiB.
// Iter = 2 K-tiles (t0->buf0, t1->buf1), 8 phases, 16 MFMA/phase/wave.
// Staging: t1 -> buf1 in P1(A x4)/P2(B 0,1)/P3(B 2,3); t0+2 -> buf0 in
// P5/P6/P7. vmcnt(0) only at P4/P8 (last loads >= 2 phases old).
// conv1: 81 tiles padded to 82 (pad tile auto-zero: amask bit9=0, B guarded).
// ---------------------------------------------------------------------------
__global__ __launch_bounds__(512, 1) void conv8p(
    const ushort_t* __restrict__ X, const ushort_t* __restrict__ Wp,
    const float* __restrict__ bias, ushort_t* __restrict__ Y0,
    ushort_t* __restrict__ Y1, const int K, const int TPT, const int NT,
    const ushort_t* __restrict__ zerot)
{
  __shared__ ushort_t lds[65536];   // buf0: A[0,16384) B[16384,32768); buf1 +32768
  const int tid = threadIdx.x;
  const int lane = tid & 63, wave = tid >> 6;
  const int wr = wave >> 2, wc = wave & 3;
  const int la = lane & 15, lb = lane >> 4;

  // XCD swizzle (256 blocks): logical L -> (g, b, n0)
  const int bid = blockIdx.x;
  const int L = ((bid & 7) << 5) + (bid >> 3);
  const int g = L >> 7;
  const int rem = L & 127;
  const int b = rem >> 1;
  const int n0 = (rem & 1) << 8;
  const int koff0 = g * (TPT << 6);

  int amask[4];
  const ushort_t* abase[4];
  const ushort_t* bbase[4];
#pragma unroll
  for (int s = 0; s < 4; ++s) {
    int idx = tid + (s << 9);
    int row = idx >> 3, ck = idx & 7;
    int i = row >> 4, j = row & 15;
    int m = 0;
#pragma unroll
    for (int tap = 0; tap < 9; ++tap) {
      int i2 = i + tap / 3 - 1, j2 = j + tap % 3 - 1;
      if (((unsigned)i2 < 16u) & ((unsigned)j2 < 16u)) m |= 1 << tap;
    }
    amask[s] = m;
    abase[s] = X + (size_t)(b * NP + row) * K + ((ck ^ (row & 7)) << 3);
    bbase[s] = Wp + (size_t)(n0 + row) * K + ((ck ^ (row & 7)) << 3);
  }

  // read offsets (elements within a buffer)
  const int ck0 = ((lb ^ (la & 7)) << 3);
  const int ck1 = (((4 + lb) ^ (la & 7)) << 3);
  const int arow = (wr * 128 + la) * 64;            // + MH*4096 + mi*1024
  const int brow = 16384 + (wc * 64 + la) * 64;     // + NH*2048 + ni*1024

  f32x4 acc[8][4];
#pragma unroll
  for (int i = 0; i < 8; ++i)
#pragma unroll
    for (int j = 0; j < 4; ++j) acc[i][j] = (f32x4){0.f, 0.f, 0.f, 0.f};

  auto tpar = [&](int t, int& tap, int& toffA, size_t& wtap) {
    tap = t / TPT;
    int kc = koff0 + ((t - tap * TPT) << 6);
    int ty = tap / 3;
    toffA = (ty * 16 + (tap - 3 * ty) - 17) * K + kc;
    wtap  = (size_t)tap * NOUT * K + kc;
  };

#define STAGE_A(S, BUFN, TAPN, TOFFN) { \
  const ushort_t* gp = ((amask[S] >> (TAPN)) & 1) ? abase[S] + (TOFFN) : zerot; \
  gl_lds16(gp, &(BUFN)[(tid + ((S) << 9)) * 8]); }
#define STAGE_B(S, BUFN, TAPN, WTAPN) { \
  const ushort_t* gp = ((TAPN) < 9) ? bbase[S] + (WTAPN) : zerot; \
  gl_lds16(gp, &(BUFN)[16384 + (tid + ((S) << 9)) * 8]); }

#define READ_A(MH, BUF) \
  Af[0][0] = *(const bf16x8*)&(BUF)[arow + (MH)*4096 + 0    + ck0]; \
  Af[0][1] = *(const bf16x8*)&(BUF)[arow + (MH)*4096 + 0    + ck1]; \
  Af[1][0] = *(const bf16x8*)&(BUF)[arow + (MH)*4096 + 1024 + ck0]; \
  Af[1][1] = *(const bf16x8*)&(BUF)[arow + (MH)*4096 + 1024 + ck1]; \
  Af[2][0] = *(const bf16x8*)&(BUF)[arow + (MH)*4096 + 2048 + ck0]; \
  Af[2][1] = *(const bf16x8*)&(BUF)[arow + (MH)*4096 + 2048 + ck1]; \
  Af[3][0] = *(const bf16x8*)&(BUF)[arow + (MH)*4096 + 3072 + ck0]; \
  Af[3][1] = *(const bf16x8*)&(BUF)[arow + (MH)*4096 + 3072 + ck1];
#define READ_B(NH, BUF) \
  Bf[0][0] = *(const bf16x8*)&(BUF)[brow + (NH)*2048 + 0    + ck0]; \
  Bf[0][1] = *(const bf16x8*)&(BUF)[brow + (NH)*2048 + 0    + ck1]; \
  Bf[1][0] = *(const bf16x8*)&(BUF)[brow + (NH)*2048 + 1024 + ck0]; \
  Bf[1][1] = *(const bf16x8*)&(BUF)[brow + (NH)*2048 + 1024 + ck1];
#define MFMA16(MH, NH) \
  acc[(MH)*4+0][(NH)*2+0] = mfma16(Af[0][0], Bf[0][0], acc[(MH)*4+0][(NH)*2+0]); \
  acc[(MH)*4+0][(NH)*2+1] = mfma16(Af[0][0], Bf[1][0], acc[(MH)*4+0][(NH)*2+1]); \
  acc[(MH)*4+1][(NH)*2+0] = mfma16(Af[1][0], Bf[0][0], acc[(MH)*4+1][(NH)*2+0]); \
  acc[(MH)*4+1][(NH)*2+1] = mfma16(Af[1][0], Bf[1][0], acc[(MH)*4+1][(NH)*2+1]); \
  acc[(MH)*4+2][(NH)*2+0] = mfma16(Af[2][0], Bf[0][0], acc[(MH)*4+2][(NH)*2+0]); \
  acc[(MH)*4+2][(NH)*2+1] = mfma16(Af[2][0], Bf[1][0], acc[(MH)*4+2][(NH)*2+1]); \
  acc[(MH)*4+3][(NH)*2+0] = mfma16(Af[3][0], Bf[0][0], acc[(MH)*4+3][(NH)*2+0]); \
  acc[(MH)*4+3][(NH)*2+1] = mfma16(Af[3][0], Bf[1][0], acc[(MH)*4+3][(NH)*2+1]); \
  acc[(MH)*4+0][(NH)*2+0] = mfma16(Af[0][1], Bf[0][1], acc[(MH)*4+0][(NH)*2+0]); \
  acc[(MH)*4+0][(NH)*2+1] = mfma16(Af[0][1], Bf[1][1], acc[(MH)*4+0][(NH)*2+1]); \
  acc[(MH)*4+1][(NH)*2+0] = mfma16(Af[1][1], Bf[0][1], acc[(MH)*4+1][(NH)*2+0]); \
  acc[(MH)*4+1][(NH)*2+1] = mfma16(Af[1][1], Bf[1][1], acc[(MH)*4+1][(NH)*2+1]); \
  acc[(MH)*4+2][(NH)*2+0] = mfma16(Af[2][1], Bf[0][1], acc[(MH)*4+2][(NH)*2+0]); \
  acc[(MH)*4+2][(NH)*2+1] = mfma16(Af[2][1], Bf[1][1], acc[(MH)*4+2][(NH)*2+1]); \
  acc[(MH)*4+3][(NH)*2+0] = mfma16(Af[3][1], Bf[0][1], acc[(MH)*4+3][(NH)*2+0]); \
  acc[(MH)*4+3][(NH)*2+1] = mfma16(Af[3][1], Bf[1][1], acc[(MH)*4+3][(NH)*2+1]);

#define PHASE_SYNC_PRE() \
  __builtin_amdgcn_s_barrier(); \
  asm volatile("s_waitcnt lgkmcnt(0)" ::: "memory"); \
  __builtin_amdgcn_sched_barrier(0); \
  __builtin_amdgcn_s_setprio(1);
#define PHASE_SYNC_POST() \
  __builtin_amdgcn_s_setprio(0); \
  __builtin_amdgcn_s_barrier();

  // prologue: stage tile 0 -> buf0
  {
    int tap0, toff0; size_t wtap0;
    tpar(0, tap0, toff0, wtap0);
    ushort_t* bufn = &lds[0];
    STAGE_A(0, bufn, tap0, toff0) STAGE_A(1, bufn, tap0, toff0)
    STAGE_A(2, bufn, tap0, toff0) STAGE_A(3, bufn, tap0, toff0)
    STAGE_B(0, bufn, tap0, wtap0) STAGE_B(1, bufn, tap0, wtap0)
    STAGE_B(2, bufn, tap0, wtap0) STAGE_B(3, bufn, tap0, wtap0)
  }
  asm volatile("s_waitcnt vmcnt(0)" ::: "memory");
  __builtin_amdgcn_s_barrier();

  const ushort_t* bufA = &lds[0];
  const ushort_t* bufB = &lds[32768];
  ushort_t* stA = &lds[32768];
  ushort_t* stC = &lds[0];

  const int niter = NT >> 1;
  for (int it = 0; it < niter; ++it) {
    const int t0 = it << 1;
    int tapB, toffB; size_t wtapB;
    tpar(t0 + 1, tapB, toffB, wtapB);
    int tapC = 0, toffC = 0; size_t wtapC = 0;
    const bool sC = (t0 + 2) < NT;
    if (sC) tpar(t0 + 2, tapC, toffC, wtapC);

    bf16x8 Af[4][2], Bf[2][2];

    // ============ tile t0 (bufA) ============
    // P1 (m0,n0): read A(m0)+B(n0); stage A(t1) x4
    READ_A(0, bufA)
    READ_B(0, bufA)
    STAGE_A(0, stA, tapB, toffB) STAGE_A(1, stA, tapB, toffB)
    STAGE_A(2, stA, tapB, toffB) STAGE_A(3, stA, tapB, toffB)
    PHASE_SYNC_PRE()
    MFMA16(0, 0)
    PHASE_SYNC_POST()
    // P2 (m0,n1): read B(n1); stage B(t1) 0,1
    READ_B(1, bufA)
    STAGE_B(0, stA, tapB, wtapB) STAGE_B(1, stA, tapB, wtapB)
    PHASE_SYNC_PRE()
    MFMA16(0, 1)
    PHASE_SYNC_POST()
    // P3 (m1,n1): read A(m1); stage B(t1) 2,3
    READ_A(1, bufA)
    STAGE_B(2, stA, tapB, wtapB) STAGE_B(3, stA, tapB, wtapB)
    PHASE_SYNC_PRE()
    MFMA16(1, 1)
    PHASE_SYNC_POST()
    // P4 (m1,n0): read B(n0); drain t1 staging (last issued P3)
    READ_B(0, bufA)
    asm volatile("s_waitcnt vmcnt(0)" ::: "memory");
    PHASE_SYNC_PRE()
    MFMA16(1, 0)
    PHASE_SYNC_POST()

    // ============ tile t0+1 (bufB) ============
    // P5 (m0,n0): stage A(t0+2) x4
    READ_A(0, bufB)
    READ_B(0, bufB)
    if (sC) {
      STAGE_A(0, stC, tapC, toffC) STAGE_A(1, stC, tapC, toffC)
      STAGE_A(2, stC, tapC, toffC) STAGE_A(3, stC, tapC, toffC)
    }
    PHASE_SYNC_PRE()
    MFMA16(0, 0)
    PHASE_SYNC_POST()
    // P6 (m0,n1): stage B(t0+2) 0,1
    READ_B(1, bufB)
    if (sC) { STAGE_B(0, stC, tapC, wtapC) STAGE_B(1, stC, tapC, wtapC) }
    PHASE_SYNC_PRE()
    MFMA16(0, 1)
    PHASE_SYNC_POST()
    // P7 (m1,n1): stage B(t0+2) 2,3
    READ_A(1, bufB)
    if (sC) { STAGE_B(2, stC, tapC, wtapC) STAGE_B(3, stC, tapC, wtapC) }
    PHASE_SYNC_PRE()
    MFMA16(1, 1)
    PHASE_SYNC_POST()
    // P8 (m1,n0): drain t0+2 staging (last issued P7)
    READ_B(0, bufB)
    asm volatile("s_waitcnt vmcnt(0)" ::: "memory");
    PHASE_SYNC_PRE()
    MFMA16(1, 0)
    PHASE_SYNC_POST()
  }

  // epilogue: bias/2 + bf16 partial-Y store
  ushort_t* Yh = g ? Y1 : Y0;
#pragma unroll
  for (int ni = 0; ni < 4; ++ni) {
    int col = n0 + wc * 64 + ni * 16 + la;
    float bv = 0.5f * bias[col];
#pragma unroll
    for (int mi = 0; mi < 8; ++mi) {
      int row = b * NP + wr * 128 + mi * 16 + lb * 4;
#pragma unroll
      for (int r = 0; r < 4; ++r)
        Yh[(size_t)(row + r) * NOUT + col] = f2bf(acc[mi][ni][r] + bv);
    }
  }
#undef STAGE_A
#undef STAGE_B
#undef READ_A
#undef READ_B
#undef MFMA16
#undef PHASE_SYNC_PRE
#undef PHASE_SYNC_POST
}

// ---------------------------------------------------------------------------
// BN stats from the two bf16 partial halves. grid 512 x block 512.
// ---------------------------------------------------------------------------
__global__ __launch_bounds__(512) void bn_stat2(
    const ushort_t* __restrict__ Y0, const ushort_t* __restrict__ Y1,
    float* __restrict__ st)
{
  const int col = threadIdx.x;
  const size_t base = (size_t)blockIdx.x * 32 * NOUT;
  float s = 0.f, q = 0.f;
  for (int r = 0; r < 32; ++r) {
    float y = b2f(Y0[base + r * NOUT + col]) + b2f(Y1[base + r * NOUT + col]);
    s += y; q += y * y;
  }
  atomicAdd(&st[col], s);
  atomicAdd(&st[512 + col], q);
}

// ---------------------------------------------------------------------------
// BN apply (sum halves) + relu + bf16, layout [m][c]. grid 4096, block 256.
// ---------------------------------------------------------------------------
__global__ __launch_bounds__(256) void bn_apply2(
    const ushort_t* __restrict__ Y0, const ushort_t* __restrict__ Y1,
    const float* __restrict__ st, const float* __restrict__ g,
    const float* __restrict__ be, ushort_t* __restrict__ Xo)
{
  const size_t idx = (size_t)blockIdx.x * 256 + threadIdx.x;
  u16x8 a = *(const u16x8*)(Y0 + idx * 8);
  u16x8 c = *(const u16x8*)(Y1 + idx * 8);
  const int c0 = (int)((idx * 8) & 511);
  u16x8 pk;
#pragma unroll
  for (int q = 0; q < 8; ++q) {
    int cc = c0 + q;
    float y = b2f(a[q]) + b2f(c[q]);
    float mu  = st[cc] * (1.f / 16384.f);
    float var = st[512 + cc] * (1.f / 16384.f) - mu * mu;
    float s = rsqrtf(var + 1e-5f) * g[cc];
    pk[q] = f2bf(fmaxf((y - mu) * s + be[cc], 0.f));
  }
  *(u16x8*)(Xo + idx * 8) = pk;
}

// ---------------------------------------------------------------------------
// BN apply + relu + bf16, transposed to FC layout Xf[b][c*256+ij].
// ---------------------------------------------------------------------------
__global__ __launch_bounds__(256) void bn_apply2_t(
    const ushort_t* __restrict__ Y0, const ushort_t* __restrict__ Y1,
    const float* __restrict__ st, const float* __restrict__ g,
    const float* __restrict__ be, ushort_t* __restrict__ Xf)
{
  __shared__ ushort_t T[64][65];
  const int c0  = blockIdx.x * 64;
  const int ij0 = blockIdx.y * 64;
  const int b   = blockIdx.z;
  const int tid = threadIdx.x;

#pragma unroll
  for (int it = 0; it < 16; ++it) {
    int e = it * 256 + tid;
    int ij = e >> 6, c = e & 63;
    int cg = c0 + c;
    size_t off = ((size_t)(b * NP + ij0 + ij)) * NOUT + cg;
    float y = b2f(Y0[off]) + b2f(Y1[off]);
    float mu  = st[cg] * (1.f / 16384.f);
    float var = st[512 + cg] * (1.f / 16384.f) - mu * mu;
    float s = rsqrtf(var + 1e-5f) * g[cg];
    T[ij][c] = f2bf(fmaxf((y - mu) * s + be[cg], 0.f));
  }
  __syncthreads();
#pragma unroll
  for (int it = 0; it < 16; ++it) {
    int e = it * 256 + tid;
    int cr = e >> 6, ijc = e & 63;
    Xf[(size_t)b * KFC + (size_t)(c0 + cr) * NP + ij0 + ijc] = T[ijc][cr];
  }
}

// ---------------------------------------------------------------------------
// FC1: (64 x 131072) bf16 @ (1024 x 131072)^T, split-K slice stores.
// ---------------------------------------------------------------------------
__device__ __forceinline__ u16x8 pack8(float4 a, float4 b) {
  u16x8 r;
  r[0] = f2bf(a.x); r[1] = f2bf(a.y); r[2] = f2bf(a.z); r[3] = f2bf(a.w);
  r[4] = f2bf(b.x); r[5] = f2bf(b.y); r[6] = f2bf(b.z); r[7] = f2bf(b.w);
  return r;
}

__global__ __launch_bounds__(256) void fc1_gemm(
    const ushort_t* __restrict__ Xf, const float* __restrict__ Wf1,
    float* __restrict__ hacc)
{
  __shared__ ushort_t As[64 * 64];
  __shared__ ushort_t Bs[64 * 64];
  const int tid = threadIdx.x, lane = tid & 63, wave = tid >> 6;
  const int la = lane & 15, lb = lane >> 4;
  const int f0 = blockIdx.x * 64;
  const int k0 = blockIdx.y * 4096;

  f32x4 acc[4];
#pragma unroll
  for (int i = 0; i < 4; ++i) acc[i] = (f32x4){0.f, 0.f, 0.f, 0.f};

  const ushort_t* xrow[2];
#pragma unroll
  for (int s = 0; s < 2; ++s) {
    int idx = tid + (s << 8);
    xrow[s] = Xf + (size_t)(idx >> 3) * KFC + k0 + (idx & 7) * 8;
  }
  const int brow = tid >> 2, kseg = (tid & 3) * 16;
  const float* wrow = Wf1 + (size_t)(f0 + brow) * KFC + k0 + kseg;

  for (int kc = 0; kc < 4096; kc += 64) {
#pragma unroll
    for (int s = 0; s < 2; ++s) {
      int idx = tid + (s << 8);
      gl_lds16(xrow[s] + kc, &As[idx * 8]);
    }
    float4 w0 = *(const float4*)(wrow + kc);
    float4 w1 = *(const float4*)(wrow + kc + 4);
    float4 w2 = *(const float4*)(wrow + kc + 8);
    float4 w3 = *(const float4*)(wrow + kc + 12);
    *(u16x8*)&Bs[brow * 64 + kseg]     = pack8(w0, w1);
    *(u16x8*)&Bs[brow * 64 + kseg + 8] = pack8(w2, w3);
    __syncthreads();
#pragma unroll
    for (int kk = 0; kk < 2; ++kk) {
      bf16x8 bfv = *(const bf16x8*)&Bs[(wave * 16 + la) * 64 + kk * 32 + lb * 8];
#pragma unroll
      for (int mi = 0; mi < 4; ++mi) {
        bf16x8 av = *(const bf16x8*)&As[(mi * 16 + la) * 64 + kk * 32 + lb * 8];
        acc[mi] = mfma16(av, bfv, acc[mi]);
      }
    }
    __syncthreads();
  }

  float* slice = hacc + (size_t)blockIdx.y * NB * NF;
#pragma unroll
  for (int mi = 0; mi < 4; ++mi) {
    int row = mi * 16 + lb * 4;
#pragma unroll
    for (int r = 0; r < 4; ++r)
      slice[(size_t)(row + r) * NF + f0 + wave * 16 + la] = acc[mi][r];
  }
}

// ---------------------------------------------------------------------------
// FC2 + bias/relu; sums the 32 fc1 k-slices. grid 64, block 256.
// ---------------------------------------------------------------------------
__global__ __launch_bounds__(256) void fc2_out(
    const float* __restrict__ hacc, const float* __restrict__ bf1,
    const float* __restrict__ Wf2, const float* __restrict__ bf2,
    float* __restrict__ out)
{
  const int b = blockIdx.x, tid = threadIdx.x;
  float a[8];
#pragma unroll
  for (int o = 0; o < 8; ++o) a[o] = 0.f;
  for (int f = tid; f < NF; f += 256) {
    float hv = bf1[f];
#pragma unroll 4
    for (int s = 0; s < KSPL; ++s)
      hv += hacc[((size_t)s * NB + b) * NF + f];
    hv = fmaxf(hv, 0.f);
#pragma unroll
    for (int o = 0; o < 8; ++o) a[o] += hv * Wf2[o * NF + f];
  }
  __shared__ float red[8][256];
#pragma unroll
  for (int o = 0; o < 8; ++o) red[o][tid] = a[o];
  __syncthreads();
  for (int s = 128; s > 0; s >>= 1) {
    if (tid < s) {
#pragma unroll
      for (int o = 0; o < 8; ++o) red[o][tid] += red[o][tid + s];
    }
    __syncthreads();
  }
  if (tid < 8) out[b * 8 + tid] = red[tid][0] + bf2[tid];
}

// ---------------------------------------------------------------------------
extern "C" void kernel_launch(void* const* d_in, const int* in_sizes, int n_in,
                              void* d_out, int out_size, void* d_ws, size_t ws_size,
                              hipStream_t stream) {
  const float* f1  = (const float*)d_in[0];
  const float* f2  = (const float*)d_in[1];
  const float* W1  = (const float*)d_in[2];
  const float* b1  = (const float*)d_in[3];
  const float* g1  = (const float*)d_in[4];
  const float* be1 = (const float*)d_in[5];
  const float* W2  = (const float*)d_in[6];
  const float* b2  = (const float*)d_in[7];
  const float* g2  = (const float*)d_in[8];
  const float* be2 = (const float*)d_in[9];
  const float* W3  = (const float*)d_in[10];
  const float* b3  = (const float*)d_in[11];
  const float* g3  = (const float*)d_in[12];
  const float* be3 = (const float*)d_in[13];
  const float* Wf1 = (const float*)d_in[14];
  const float* bf1 = (const float*)d_in[15];
  const float* Wf2 = (const float*)d_in[16];
  const float* bf2 = (const float*)d_in[17];
  float* out = (float*)d_out;

  char* ws = (char*)d_ws;
  size_t off = 0;
  auto alloc = [&](size_t bytes) -> void* {
    void* p = ws + off;
    off += (bytes + 255) & ~(size_t)255;
    return p;
  };

  // zeroed region: zero tile + BN stats
  ushort_t* zerot = (ushort_t*)alloc(256);
  float* st1  = (float*)alloc(1024 * 4);
  float* st2  = (float*)alloc(1024 * 4);
  float* st3  = (float*)alloc(1024 * 4);
  const size_t zero_bytes = off;

  float* hacc = (float*)alloc((size_t)KSPL * NB * NF * 4);  // fully written
  const size_t SZ_AT   = (size_t)NB * NP * NC * 2;
  const size_t SZ_COST = (size_t)NB * NP * KP1 * 2;
  const size_t SZ_WP1  = (size_t)9 * NOUT * KP1 * 2;
  const size_t SZ_WP23 = (size_t)9 * NOUT * 512 * 2;
  ushort_t* AT    = (ushort_t*)alloc(SZ_AT);
  ushort_t* N2T   = (ushort_t*)alloc(SZ_AT);
  ushort_t* costT = (ushort_t*)alloc(SZ_COST);
  ushort_t* Wp1   = (ushort_t*)alloc(SZ_WP1);
  ushort_t* Wp2   = (ushort_t*)alloc(SZ_WP23);
  ushort_t* Wp3   = (ushort_t*)alloc(SZ_WP23);
  ushort_t* Yh0   = (ushort_t*)alloc((size_t)NROWS * NOUT * 2);
  ushort_t* Yh1   = (ushort_t*)alloc((size_t)NROWS * NOUT * 2);
  ushort_t* Xbuf  = (ushort_t*)alloc((size_t)NROWS * NOUT * 2);
  ushort_t* Xf    = (ushort_t*)alloc((size_t)NB * KFC * 2);

  hipMemsetAsync(ws, 0, zero_bytes, stream);
  hipMemsetAsync(costT, 0, SZ_COST, stream);

  l2norm_t<<<dim3(64, 2), 256, 0, stream>>>(f1, f2, AT, N2T);

  pack_w<<<(9 * NOUT * KP1 + 255) / 256, 256, 0, stream>>>(W1, Wp1, 1089, KP1, 9 * NOUT * KP1);
  pack_w<<<(9 * NOUT * 512 + 255) / 256, 256, 0, stream>>>(W2, Wp2, 512, 512, 9 * NOUT * 512);
  pack_w<<<(9 * NOUT * 512 + 255) / 256, 256, 0, stream>>>(W3, Wp3, 512, 512, 9 * NOUT * 512);

  cv_gemm<<<dim3(18, 2, 64), 256, 0, stream>>>(AT, N2T, costT, zerot);

  conv8p<<<256, 512, 0, stream>>>(costT, Wp1, b1, Yh0, Yh1, KP1, 9, 82, zerot);
  bn_stat2<<<512, 512, 0, stream>>>(Yh0, Yh1, st1);
  bn_apply2<<<4096, 256, 0, stream>>>(Yh0, Yh1, st1, g1, be1, Xbuf);

  conv8p<<<256, 512, 0, stream>>>(Xbuf, Wp2, b2, Yh0, Yh1, 512, 4, 36, zerot);
  bn_stat2<<<512, 512, 0, stream>>>(Yh0, Yh1, st2);
  bn_apply2<<<4096, 256, 0, stream>>>(Yh0, Yh1, st2, g2, be2, Xbuf);

  conv8p<<<256, 512, 0, stream>>>(Xbuf, Wp3, b3, Yh0, Yh1, 512, 4, 36, zerot);
  bn_stat2<<<512, 512, 0, stream>>>(Yh0, Yh1, st3);
  bn_apply2_t<<<dim3(8, 4, 64), 256, 0, stream>>>(Yh0, Yh1, st3, g3, be3, Xf);

  fc1_gemm<<<dim3(16, KSPL), 256, 0, stream>>>(Xf, Wf1, hacc);
  fc2_out<<<64, 256, 0, stream>>>(hacc, bf1, Wf2, bf2, out);

  (void)in_sizes; (void)n_in; (void)out_size; (void)ws_size;
}